// Round 17
// baseline (838.755 us; speedup 1.0000x reference)
//
#include <hip/hip_runtime.h>

#define D 128
#define CLS 3
#define LAY 3
#define NBKT 8

typedef __attribute__((ext_vector_type(4))) float evf4;
typedef __attribute__((ext_vector_type(8))) short bf16x8;
typedef __attribute__((ext_vector_type(4))) float f32x4;

__device__ __forceinline__ unsigned short bf16rne(float x) {
  unsigned b = __float_as_uint(x);
  unsigned r = b + 0x7FFFu + ((b >> 16) & 1u);
  return (unsigned short)(r >> 16);
}
__device__ __forceinline__ float bf16tof(unsigned short h) {
  return __uint_as_float(((unsigned)h) << 16);
}

// ---- parallel padded-count scan, 3 phases ----
__global__ __launch_bounds__(256) void k_scanA(const int* __restrict__ cnt,
                                               int* __restrict__ bsum, int N) {
  int i = blockIdx.x * 256 + threadIdx.x;
  int v = (i < N) ? ((cnt[i] + 15) & ~15) : 0;
#pragma unroll
  for (int o = 32; o > 0; o >>= 1) v += __shfl_xor(v, o, 64);
  __shared__ int ws[4];
  if ((threadIdx.x & 63) == 0) ws[threadIdx.x >> 6] = v;
  __syncthreads();
  if (threadIdx.x == 0) bsum[blockIdx.x] = ws[0] + ws[1] + ws[2] + ws[3];
}

__global__ __launch_bounds__(1024) void k_scanB(const int* __restrict__ bsum,
                                                int* __restrict__ boff,
                                                int* __restrict__ rptrN, int nb) {
  const int t = threadIdx.x;
  const int lane = t & 63, wid = t >> 6;
  int v = (t < nb) ? bsum[t] : 0;
  int s = v;
#pragma unroll
  for (int o = 1; o < 64; o <<= 1) {
    int u = __shfl_up(s, o, 64);
    if (lane >= o) s += u;
  }
  __shared__ int ws[16];
  if (lane == 63) ws[wid] = s;
  __syncthreads();
  if (wid == 0 && lane < 16) {
    int w = ws[lane];
#pragma unroll
    for (int o = 1; o < 16; o <<= 1) {
      int u = __shfl_up(w, o, 16);
      if (lane >= o) w += u;
    }
    ws[lane] = w;
  }
  __syncthreads();
  int add = wid ? ws[wid - 1] : 0;
  if (t < nb) boff[t] = add + s - v;
  if (t == nb - 1) *rptrN = add + s;
}

__global__ __launch_bounds__(256) void k_scanC(const int* __restrict__ cnt,
                                               const int* __restrict__ boff,
                                               int* __restrict__ rptr2,
                                               float* __restrict__ dinv,
                                               unsigned short* __restrict__ srcs, int N) {
  const int t = threadIdx.x;
  const int i = blockIdx.x * 256 + t;
  const int lane = t & 63, wid = t >> 6;
  const int cv = (i < N) ? cnt[i] : 0;
  const int v = (i < N) ? ((cv + 15) & ~15) : 0;
  int s = v;
#pragma unroll
  for (int o = 1; o < 64; o <<= 1) {
    int u = __shfl_up(s, o, 64);
    if (lane >= o) s += u;
  }
  __shared__ int ws[4];
  if (lane == 63) ws[wid] = s;
  __syncthreads();
  int add = 0;
  if (wid > 0) add += ws[0];
  if (wid > 1) add += ws[1];
  if (wid > 2) add += ws[2];
  if (i < N) {
    const int base = boff[blockIdx.x] + add + s - v;
    rptr2[i] = base;
    dinv[i] = rsqrtf((float)(cv + 1));
    for (int e = base + cv; e < base + v; ++e) srcs[e] = (unsigned short)N;
  }
}

// phase A: per-node degree count + bin edges into 8 col-range buckets
__global__ __launch_bounds__(256) void k_bin(const int* __restrict__ row,
                                             const int* __restrict__ col,
                                             int* __restrict__ cnt,
                                             int* __restrict__ bfill,
                                             unsigned* __restrict__ pairs,
                                             int E, float bscale, int bshift) {
  __shared__ int lh[NBKT], gbase[NBKT], lcur[NBKT];
  const int tid = threadIdx.x;
  const int chunk = (E + gridDim.x - 1) / gridDim.x;
  const int s0 = blockIdx.x * chunk;
  const int s1 = min(s0 + chunk, E);
  if (tid < NBKT) lh[tid] = 0;
  __syncthreads();
  for (int e = s0 + tid; e < s1; e += 256) {
    int c = col[e];
    atomicAdd(&cnt[c], 1);
    int b = min(NBKT - 1, (int)((float)c * bscale));
    atomicAdd(&lh[b], 1);
  }
  __syncthreads();
  if (tid < NBKT) {
    gbase[tid] = atomicAdd(&bfill[tid], lh[tid]);
    lcur[tid] = 0;
  }
  __syncthreads();
  for (int e = s0 + tid; e < s1; e += 256) {
    int c = col[e], r = row[e];
    int b = min(NBKT - 1, (int)((float)c * bscale));
    int off = atomicAdd(&lcur[b], 1);
    pairs[(b << bshift) + gbase[b] + off] = ((unsigned)r << 16) | (unsigned)c;
  }
}

// phase B: XCD-affine scatter into padded CSR (bucket b on blocks with blockIdx&7==b)
__global__ __launch_bounds__(256) void k_fill2(const unsigned* __restrict__ pairs,
                                               const int* __restrict__ bfill,
                                               const int* __restrict__ rptr2,
                                               int* __restrict__ fillc,
                                               unsigned short* __restrict__ srcs,
                                               int bshift) {
  const int b = blockIdx.x & 7;
  const int bi = blockIdx.x >> 3;
  const int cap = bfill[b];
  const int stride = (gridDim.x >> 3) * blockDim.x;
  const unsigned* __restrict__ bp = pairs + ((size_t)b << bshift);
  for (int idx = bi * blockDim.x + threadIdx.x; idx < cap; idx += stride) {
    unsigned p = bp[idx];
    int c = (int)(p & 0xFFFFu);
    int pos = rptr2[c] + atomicAdd(&fillc[c], 1);
    srcs[pos] = (unsigned short)(p >> 16);
  }
}

// zero the 8 sentinel rows of each of the 3 slice tables
__global__ void k_zsent(float* __restrict__ Tall, int N) {
  int t = blockIdx.x * blockDim.x + threadIdx.x;
  if (t < CLS * 8 * 16) {
    int c = t / 128, rem = t % 128;
    int s = rem / 16, f = rem % 16;
    Tall[((size_t)c * 8 + s) * (size_t)(N + 1) * 16 + (size_t)N * 16 + f] = 0.f;
  }
}

// split conv_w into bf16 hi/lo, TRANSPOSED: WhT[cl][col][k]
__global__ void k_wsplit(const float* __restrict__ W, unsigned short* __restrict__ WhT,
                         unsigned short* __restrict__ WlT, int total) {
  int idx = blockIdx.x * blockDim.x + threadIdx.x;
  if (idx >= total) return;
  int cl = idx >> 14;
  int rem = idx & 16383;
  int c = rem >> 7, k = rem & 127;
  float w = W[(size_t)cl * 16384 + k * 128 + c];
  unsigned short h = bf16rne(w);
  WhT[idx] = h;
  WlT[idx] = bf16rne(w - bf16tof(h));
}

// ---- T0 = x * dinv, slice-major [8][N+1][16] ----
__global__ __launch_bounds__(256) void k_scale(const float* __restrict__ x,
                                               const float* __restrict__ dinv,
                                               float* __restrict__ T, int N) {
  const int s = blockIdx.y;
  const int i = blockIdx.x * 64 + (threadIdx.x >> 2);
  const int f = threadIdx.x & 3;
  if (i < N) {
    float4 v = *(const float4*)&x[(size_t)i * 128 + s * 16 + f * 4];
    float d = dinv[i];
    v.x *= d; v.y *= d; v.z *= d; v.w *= d;
    *(float4*)&T[((size_t)s * (N + 1) + i) * 16 + f * 4] = v;
  }
}

// ---- XCD-sliced gather, fused over classes (blockIdx.y = class); fp32 full-line out ----
__global__ __launch_bounds__(256, 4) void k_gather(const float* __restrict__ Tbase, long tstride,
                                                   const int* __restrict__ rptr2,
                                                   const unsigned short* __restrict__ srcs,
                                                   const float* __restrict__ dinv,
                                                   float* __restrict__ Zbase, long zstride,
                                                   int N) {
  const int s = blockIdx.x & 7;
  const int chunk = blockIdx.x >> 3;
  const int i = chunk * 64 + (threadIdx.x >> 2);
  const int f = threadIdx.x & 3;
  if (i >= N) return;
  const float* __restrict__ T = Tbase + (size_t)blockIdx.y * tstride;
  float* __restrict__ Z = Zbase + (size_t)blockIdx.y * zstride;
  const evf4* __restrict__ Ts = (const evf4*)(T + (size_t)s * (N + 1) * 16);
  const int e0 = rptr2[i], e1 = rptr2[i + 1];
  evf4 a0 = Ts[(size_t)i * 4 + f];  // self term
  evf4 a1 = (evf4)0.f, a2 = (evf4)0.f, a3 = (evf4)0.f;
  uint4 I0 = make_uint4(0, 0, 0, 0), I1 = I0;
  if (e0 < e1) {
    I0 = *(const uint4*)(srcs + e0);
    I1 = *(const uint4*)(srcs + e0 + 8);
  }
  for (int eb = e0; eb < e1; eb += 16) {
    uint4 I0n = I0, I1n = I1;
    if (eb + 16 < e1) {
      I0n = *(const uint4*)(srcs + eb + 16);
      I1n = *(const uint4*)(srcs + eb + 24);
    }
    const int j0  = (int)(I0.x & 0xFFFFu), j1  = (int)(I0.x >> 16);
    const int j2  = (int)(I0.y & 0xFFFFu), j3  = (int)(I0.y >> 16);
    const int j4  = (int)(I0.z & 0xFFFFu), j5  = (int)(I0.z >> 16);
    const int j6  = (int)(I0.w & 0xFFFFu), j7  = (int)(I0.w >> 16);
    const int j8  = (int)(I1.x & 0xFFFFu), j9  = (int)(I1.x >> 16);
    const int j10 = (int)(I1.y & 0xFFFFu), j11 = (int)(I1.y >> 16);
    const int j12 = (int)(I1.z & 0xFFFFu), j13 = (int)(I1.z >> 16);
    const int j14 = (int)(I1.w & 0xFFFFu), j15 = (int)(I1.w >> 16);
    evf4 v0  = Ts[(size_t)j0  * 4 + f];
    evf4 v1  = Ts[(size_t)j1  * 4 + f];
    evf4 v2  = Ts[(size_t)j2  * 4 + f];
    evf4 v3  = Ts[(size_t)j3  * 4 + f];
    evf4 v4  = Ts[(size_t)j4  * 4 + f];
    evf4 v5  = Ts[(size_t)j5  * 4 + f];
    evf4 v6  = Ts[(size_t)j6  * 4 + f];
    evf4 v7  = Ts[(size_t)j7  * 4 + f];
    evf4 v8  = Ts[(size_t)j8  * 4 + f];
    evf4 v9  = Ts[(size_t)j9  * 4 + f];
    evf4 v10 = Ts[(size_t)j10 * 4 + f];
    evf4 v11 = Ts[(size_t)j11 * 4 + f];
    evf4 v12 = Ts[(size_t)j12 * 4 + f];
    evf4 v13 = Ts[(size_t)j13 * 4 + f];
    evf4 v14 = Ts[(size_t)j14 * 4 + f];
    evf4 v15 = Ts[(size_t)j15 * 4 + f];
    asm volatile("" :: "v"(v0), "v"(v1), "v"(v2), "v"(v3),
                       "v"(v4), "v"(v5), "v"(v6), "v"(v7),
                       "v"(v8), "v"(v9), "v"(v10), "v"(v11),
                       "v"(v12), "v"(v13), "v"(v14), "v"(v15));
    __builtin_amdgcn_sched_barrier(0);
    a0 += v0;  a1 += v1;  a2 += v2;  a3 += v3;
    a0 += v4;  a1 += v5;  a2 += v6;  a3 += v7;
    a0 += v8;  a1 += v9;  a2 += v10; a3 += v11;
    a0 += v12; a1 += v13; a2 += v14; a3 += v15;
    I0 = I0n; I1 = I1n;
  }
  const float d = dinv[i];
  evf4 r = (a0 + a1 + a2 + a3) * d;
  *(evf4*)&Z[(size_t)i * 128 + s * 16 + f * 4] = r;
}

// ---- split-bf16 MFMA GEMM (emulated fp32), A split in-kernel from fp32 ----
// C = Ah@Wh + Ah@Wl + Al@Wh. 128x128 tile, 4 waves, K-step 32.
// LDS pad 36 u16 (72B row stride: 16 lanes -> 16 distinct even banks, 2-way free);
// __launch_bounds__(256,4) caps VGPR at 128 -> 4 blocks/CU.
template <int MODE>
__global__ __launch_bounds__(256, 4) void k_gemm3m(
    const float* __restrict__ Abase, long astride,
    const unsigned short* __restrict__ WhT, const unsigned short* __restrict__ WlT,
    int layer, const float* __restrict__ bl, const float* __restrict__ dinv,
    float* __restrict__ Obase, long ostride, int N) {
  __shared__ unsigned short Ash[128 * 36], Asl[128 * 36];
  __shared__ unsigned short Wsh[128 * 36], Wsl[128 * 36];
  __shared__ float red[128][2];

  const int c = blockIdx.y;
  const float* __restrict__ A = Abase + (size_t)c * astride;
  const size_t wslab = (size_t)(c * LAY + layer) * 16384;
  const float* __restrict__ bias = bl + (size_t)(c * LAY + layer) * D;
  float* __restrict__ Out = Obase + (size_t)c * ostride;

  const int tid = threadIdx.x;
  const int w = tid >> 6, l = tid & 63;
  const int wr = w >> 1, wc = w & 1;
  const int lg = l >> 4, li = l & 15;
  const int m0 = blockIdx.x * 128;

  f32x4 acc[4][4];
#pragma unroll
  for (int i = 0; i < 4; ++i)
#pragma unroll
    for (int j = 0; j < 4; ++j) acc[i][j] = (f32x4)0.f;

  const int srow = tid >> 1;
  const int half = tid & 1;
  const bool rowok = (m0 + srow) < N;

  for (int kc = 0; kc < 128; kc += 32) {
    float fa[16];
#pragma unroll
    for (int j = 0; j < 16; ++j) fa[j] = 0.f;
    if (rowok) {
      const size_t ab = (size_t)(m0 + srow) * 128 + kc + half * 16;
      *(float4*)&fa[0]  = *(const float4*)&A[ab];
      *(float4*)&fa[4]  = *(const float4*)&A[ab + 4];
      *(float4*)&fa[8]  = *(const float4*)&A[ab + 8];
      *(float4*)&fa[12] = *(const float4*)&A[ab + 12];
    }
    const size_t wb = wslab + (size_t)srow * 128 + kc + half * 16;
    uint4 wh0 = *(const uint4*)&WhT[wb];
    uint4 wh1 = *(const uint4*)&WhT[wb + 8];
    uint4 wl0 = *(const uint4*)&WlT[wb];
    uint4 wl1 = *(const uint4*)&WlT[wb + 8];

    unsigned hpk[8], lpk[8];
#pragma unroll
    for (int j = 0; j < 8; ++j) {
      unsigned short h0 = bf16rne(fa[2 * j]);
      unsigned short h1 = bf16rne(fa[2 * j + 1]);
      float l0 = fa[2 * j] - bf16tof(h0);
      float l1 = fa[2 * j + 1] - bf16tof(h1);
      hpk[j] = (unsigned)h0 | ((unsigned)h1 << 16);
      lpk[j] = (unsigned)bf16rne(l0) | ((unsigned)bf16rne(l1) << 16);
    }
    if (kc) __syncthreads();
    *(uint4*)&Ash[srow * 36 + half * 16]     = make_uint4(hpk[0], hpk[1], hpk[2], hpk[3]);
    *(uint4*)&Ash[srow * 36 + half * 16 + 8] = make_uint4(hpk[4], hpk[5], hpk[6], hpk[7]);
    *(uint4*)&Asl[srow * 36 + half * 16]     = make_uint4(lpk[0], lpk[1], lpk[2], lpk[3]);
    *(uint4*)&Asl[srow * 36 + half * 16 + 8] = make_uint4(lpk[4], lpk[5], lpk[6], lpk[7]);
    *(uint4*)&Wsh[srow * 36 + half * 16]     = wh0;
    *(uint4*)&Wsh[srow * 36 + half * 16 + 8] = wh1;
    *(uint4*)&Wsl[srow * 36 + half * 16]     = wl0;
    *(uint4*)&Wsl[srow * 36 + half * 16 + 8] = wl1;
    __syncthreads();

    bf16x8 fah[4], fal[4];
#pragma unroll
    for (int rf = 0; rf < 4; ++rf) {
      const int arow = wr * 64 + rf * 16 + li;
      fah[rf] = *(const bf16x8*)&Ash[arow * 36 + lg * 8];
      fal[rf] = *(const bf16x8*)&Asl[arow * 36 + lg * 8];
    }
#pragma unroll
    for (int cf = 0; cf < 4; ++cf) {
      const int bcol = wc * 64 + cf * 16 + li;
      bf16x8 fbh = *(const bf16x8*)&Wsh[bcol * 36 + lg * 8];
      bf16x8 fbl = *(const bf16x8*)&Wsl[bcol * 36 + lg * 8];
#pragma unroll
      for (int rf = 0; rf < 4; ++rf) {
        acc[rf][cf] = __builtin_amdgcn_mfma_f32_16x16x32_bf16(fah[rf], fbh, acc[rf][cf], 0, 0, 0);
        acc[rf][cf] = __builtin_amdgcn_mfma_f32_16x16x32_bf16(fah[rf], fbl, acc[rf][cf], 0, 0, 0);
        acc[rf][cf] = __builtin_amdgcn_mfma_f32_16x16x32_bf16(fal[rf], fbh, acc[rf][cf], 0, 0, 0);
      }
    }
  }
  __syncthreads();

  // epilogue: bias, row L2-norm (cross-lane + cross-wave), relu, (dinv), store
  float bj[4];
#pragma unroll
  for (int cf = 0; cf < 4; ++cf) bj[cf] = bias[wc * 64 + cf * 16 + li];
#pragma unroll
  for (int rf = 0; rf < 4; ++rf) {
#pragma unroll
    for (int r = 0; r < 4; ++r) {
      float sq = 0.f;
#pragma unroll
      for (int cf = 0; cf < 4; ++cf) {
        float v = acc[rf][cf][r] + bj[cf];
        acc[rf][cf][r] = v;
        sq = fmaf(v, v, sq);
      }
#pragma unroll
      for (int m = 1; m < 16; m <<= 1) sq += __shfl_xor(sq, m, 16);
      if (li == 0) red[wr * 64 + rf * 16 + lg * 4 + r][wc] = sq;
    }
  }
  __syncthreads();
#pragma unroll
  for (int rf = 0; rf < 4; ++rf) {
#pragma unroll
    for (int r = 0; r < 4; ++r) {
      const int rrow = wr * 64 + rf * 16 + lg * 4 + r;
      const int grow = m0 + rrow;
      if (grow >= N) continue;
      float rsum = red[rrow][0] + red[rrow][1];
      float sc = 1.0f / fmaxf(sqrtf(rsum), 1e-12f);
      if (MODE == 0) sc *= dinv[grow];
#pragma unroll
      for (int cf = 0; cf < 4; ++cf) {
        float v = fmaxf(acc[rf][cf][r] * sc, 0.f);
        if (MODE == 0) {
          const int sidx = wc * 4 + cf;
          Out[((size_t)sidx * (N + 1) + grow) * 16 + li] = v;
        } else {
          Out[(size_t)grow * 128 + wc * 64 + cf * 16 + li] = v;
        }
      }
    }
  }
}

// ------------- batched head: pool + lin1 + ReLU + lin2 (blockIdx.y = class) -------------
__device__ __forceinline__ int lowerb(const int* __restrict__ a, int n, int v) {
  int lo = 0, hi = n;
  while (lo < hi) {
    int m = (lo + hi) >> 1;
    if (a[m] < v) lo = m + 1; else hi = m;
  }
  return lo;
}

__global__ __launch_bounds__(128) void k_head(const float* __restrict__ Hall, long hstride,
                                              const int* __restrict__ batch, int N,
                                              const float* __restrict__ l1w,
                                              const float* __restrict__ l1b,
                                              const float* __restrict__ l2w,
                                              const float* __restrict__ l2b,
                                              float* __restrict__ out, int G) {
  const int g = blockIdx.x;
  const int c = blockIdx.y;
  const int t = threadIdx.x;
  const float* __restrict__ h = Hall + (size_t)c * hstride;
  const float* __restrict__ w1 = l1w + (size_t)c * D * D;
  const float* __restrict__ w2 = l2w + (size_t)c * D;
  int lo = lowerb(batch, N, g);
  int hi = lowerb(batch, N, g + 1);
  float p = 0.f;
  for (int i = lo; i < hi; ++i) p += h[(size_t)i * 128 + t];
  __shared__ float pl[128];
  pl[t] = p;
  __syncthreads();
  float z = l1b[(size_t)c * D + t];
#pragma unroll 8
  for (int k = 0; k < 128; ++k) z = fmaf(pl[k], w1[k * 128 + t], z);
  z = fmaxf(z, 0.f);
  float o = z * w2[t];
#pragma unroll
  for (int off = 32; off > 0; off >>= 1) o += __shfl_xor(o, off, 64);
  __shared__ float s2[2];
  if ((t & 63) == 0) s2[t >> 6] = o;
  __syncthreads();
  if (t == 0) out[(size_t)g * CLS + c] = s2[0] + s2[1] + l2b[c];
}

extern "C" void kernel_launch(void* const* d_in, const int* in_sizes, int n_in,
                              void* d_out, int out_size, void* d_ws, size_t ws_size,
                              hipStream_t stream) {
  const float* x = (const float*)d_in[0];
  const int* eidx = (const int*)d_in[1];
  const int* batch = (const int*)d_in[2];
  const float* conv_w = (const float*)d_in[3];
  const float* conv_b = (const float*)d_in[4];
  const float* lin1_w = (const float*)d_in[5];
  const float* lin1_b = (const float*)d_in[6];
  const float* lin2_w = (const float*)d_in[7];
  const float* lin2_b = (const float*)d_in[8];
  float* out = (float*)d_out;

  const int N = in_sizes[0] / D;
  const int E = in_sizes[1] / 2;
  const int G = out_size / CLS;
  const int* row = eidx;
  const int* col = eidx + E;

  int bshift = 10;
  while ((1 << bshift) < E / NBKT + 32768) ++bshift;
  const long TS = (long)(N + 1) * 128;  // per-class slice-table stride (floats)
  const long ZS = (long)N * 128;        // per-class row-major stride (floats)

  char* ws = (char*)d_ws;
  size_t off = 0;
  auto alloc = [&](size_t bytes) -> void* {
    void* p = ws + off;
    off += (bytes + 255) & ~(size_t)255;
    return p;
  };
  float* Zall = (float*)alloc((size_t)CLS * ZS * 4);
  float* Tall = (float*)alloc((size_t)CLS * TS * 4);
  unsigned short* WhT = (unsigned short*)alloc((size_t)CLS * LAY * D * D * 2);
  unsigned short* WlT = (unsigned short*)alloc((size_t)CLS * LAY * D * D * 2);
  unsigned short* srcs = (unsigned short*)alloc(((size_t)E + 16 * (size_t)N + 64) * 2);
  int* cnt    = (int*)alloc(((size_t)N * 2 + NBKT) * 4);
  int* fillc  = cnt + N;
  int* bfill  = cnt + 2 * N;
  int* rptr2  = (int*)alloc((size_t)(N + 1) * 4);
  float* dinv = (float*)alloc((size_t)N * 4);
  int* bsum   = (int*)alloc(1024 * 4 * 2);
  int* boff   = bsum + 1024;
  unsigned* pairs = (unsigned*)Tall;  // alias: dead before k_zsent/k_scale
  (void)ws_size; (void)n_in;

  hipMemsetAsync(cnt, 0, ((size_t)N * 2 + NBKT) * 4, stream);
  const int wtot = CLS * LAY * D * D;
  const int sb = (N + 255) / 256;
  k_bin<<<1024, 256, 0, stream>>>(row, col, cnt, bfill, pairs, E, (float)NBKT / (float)N, bshift);
  k_scanA<<<sb, 256, 0, stream>>>(cnt, bsum, N);
  k_scanB<<<1, 1024, 0, stream>>>(bsum, boff, rptr2 + N, sb);
  k_scanC<<<sb, 256, 0, stream>>>(cnt, boff, rptr2, dinv, srcs, N);
  k_fill2<<<1024, 256, 0, stream>>>(pairs, bfill, rptr2, fillc, srcs, bshift);
  k_zsent<<<2, 256, 0, stream>>>(Tall, N);
  k_wsplit<<<(wtot + 255) / 256, 256, 0, stream>>>(conv_w, WhT, WlT, wtot);

  const int NB64 = (N + 63) / 64;
  const int gb = (N + 127) / 128;
  float* Z0 = Zall;

  // shared layer 0
  k_scale<<<dim3(NB64, 8), 256, 0, stream>>>(x, dinv, Tall, N);
  k_gather<<<dim3(NB64 * 8, 1), 256, 0, stream>>>(Tall, 0L, rptr2, srcs, dinv, Z0, 0L, N);

  // layer 1 (A shared across classes)
  k_gemm3m<0><<<dim3(gb, CLS), 256, 0, stream>>>(Z0, 0L, WhT, WlT, 0,
                                                 conv_b, dinv, Tall, TS, N);
  k_gather<<<dim3(NB64 * 8, CLS), 256, 0, stream>>>(Tall, TS, rptr2, srcs, dinv, Zall, ZS, N);

  // layer 2
  k_gemm3m<0><<<dim3(gb, CLS), 256, 0, stream>>>(Zall, ZS, WhT, WlT, 1,
                                                 conv_b, dinv, Tall, TS, N);
  k_gather<<<dim3(NB64 * 8, CLS), 256, 0, stream>>>(Tall, TS, rptr2, srcs, dinv, Zall, ZS, N);

  // layer 3 -> H (row-major fp32, stored in the table slots)
  k_gemm3m<1><<<dim3(gb, CLS), 256, 0, stream>>>(Zall, ZS, WhT, WlT, 2,
                                                 conv_b, dinv, Tall, TS, N);

  // heads
  k_head<<<dim3(G, CLS), 128, 0, stream>>>(Tall, TS, batch, N,
                                           lin1_w, lin1_b, lin2_w, lin2_b, out, G);
}

// Round 18
// 764.536 us; speedup vs baseline: 1.0971x; 1.0971x over previous
//
#include <hip/hip_runtime.h>

#define D 128
#define CLS 3
#define LAY 3
#define NBKT 8

typedef __attribute__((ext_vector_type(4))) float evf4;
typedef __attribute__((ext_vector_type(8))) short bf16x8;
typedef __attribute__((ext_vector_type(4))) float f32x4;

__device__ __forceinline__ unsigned short bf16rne(float x) {
  unsigned b = __float_as_uint(x);
  unsigned r = b + 0x7FFFu + ((b >> 16) & 1u);
  return (unsigned short)(r >> 16);
}
__device__ __forceinline__ float bf16tof(unsigned short h) {
  return __uint_as_float(((unsigned)h) << 16);
}

// ---- parallel padded-count scan, 3 phases ----
__global__ __launch_bounds__(256) void k_scanA(const int* __restrict__ cnt,
                                               int* __restrict__ bsum, int N) {
  int i = blockIdx.x * 256 + threadIdx.x;
  int v = (i < N) ? ((cnt[i] + 15) & ~15) : 0;
#pragma unroll
  for (int o = 32; o > 0; o >>= 1) v += __shfl_xor(v, o, 64);
  __shared__ int ws[4];
  if ((threadIdx.x & 63) == 0) ws[threadIdx.x >> 6] = v;
  __syncthreads();
  if (threadIdx.x == 0) bsum[blockIdx.x] = ws[0] + ws[1] + ws[2] + ws[3];
}

__global__ __launch_bounds__(1024) void k_scanB(const int* __restrict__ bsum,
                                                int* __restrict__ boff,
                                                int* __restrict__ rptrN, int nb) {
  const int t = threadIdx.x;
  const int lane = t & 63, wid = t >> 6;
  int v = (t < nb) ? bsum[t] : 0;
  int s = v;
#pragma unroll
  for (int o = 1; o < 64; o <<= 1) {
    int u = __shfl_up(s, o, 64);
    if (lane >= o) s += u;
  }
  __shared__ int ws[16];
  if (lane == 63) ws[wid] = s;
  __syncthreads();
  if (wid == 0 && lane < 16) {
    int w = ws[lane];
#pragma unroll
    for (int o = 1; o < 16; o <<= 1) {
      int u = __shfl_up(w, o, 16);
      if (lane >= o) w += u;
    }
    ws[lane] = w;
  }
  __syncthreads();
  int add = wid ? ws[wid - 1] : 0;
  if (t < nb) boff[t] = add + s - v;
  if (t == nb - 1) *rptrN = add + s;
}

__global__ __launch_bounds__(256) void k_scanC(const int* __restrict__ cnt,
                                               const int* __restrict__ boff,
                                               int* __restrict__ rptr2,
                                               float* __restrict__ dinv,
                                               unsigned short* __restrict__ srcs, int N) {
  const int t = threadIdx.x;
  const int i = blockIdx.x * 256 + t;
  const int lane = t & 63, wid = t >> 6;
  const int cv = (i < N) ? cnt[i] : 0;
  const int v = (i < N) ? ((cv + 15) & ~15) : 0;
  int s = v;
#pragma unroll
  for (int o = 1; o < 64; o <<= 1) {
    int u = __shfl_up(s, o, 64);
    if (lane >= o) s += u;
  }
  __shared__ int ws[4];
  if (lane == 63) ws[wid] = s;
  __syncthreads();
  int add = 0;
  if (wid > 0) add += ws[0];
  if (wid > 1) add += ws[1];
  if (wid > 2) add += ws[2];
  if (i < N) {
    const int base = boff[blockIdx.x] + add + s - v;
    rptr2[i] = base;
    dinv[i] = rsqrtf((float)(cv + 1));
    for (int e = base + cv; e < base + v; ++e) srcs[e] = (unsigned short)N;
  }
}

// phase A: per-node degree count + bin edges into 8 col-range buckets
__global__ __launch_bounds__(256) void k_bin(const int* __restrict__ row,
                                             const int* __restrict__ col,
                                             int* __restrict__ cnt,
                                             int* __restrict__ bfill,
                                             unsigned* __restrict__ pairs,
                                             int E, float bscale, int bshift) {
  __shared__ int lh[NBKT], gbase[NBKT], lcur[NBKT];
  const int tid = threadIdx.x;
  const int chunk = (E + gridDim.x - 1) / gridDim.x;
  const int s0 = blockIdx.x * chunk;
  const int s1 = min(s0 + chunk, E);
  if (tid < NBKT) lh[tid] = 0;
  __syncthreads();
  for (int e = s0 + tid; e < s1; e += 256) {
    int c = col[e];
    atomicAdd(&cnt[c], 1);
    int b = min(NBKT - 1, (int)((float)c * bscale));
    atomicAdd(&lh[b], 1);
  }
  __syncthreads();
  if (tid < NBKT) {
    gbase[tid] = atomicAdd(&bfill[tid], lh[tid]);
    lcur[tid] = 0;
  }
  __syncthreads();
  for (int e = s0 + tid; e < s1; e += 256) {
    int c = col[e], r = row[e];
    int b = min(NBKT - 1, (int)((float)c * bscale));
    int off = atomicAdd(&lcur[b], 1);
    pairs[(b << bshift) + gbase[b] + off] = ((unsigned)r << 16) | (unsigned)c;
  }
}

// phase B: XCD-affine scatter into padded CSR (bucket b on blocks with blockIdx&7==b)
__global__ __launch_bounds__(256) void k_fill2(const unsigned* __restrict__ pairs,
                                               const int* __restrict__ bfill,
                                               const int* __restrict__ rptr2,
                                               int* __restrict__ fillc,
                                               unsigned short* __restrict__ srcs,
                                               int bshift) {
  const int b = blockIdx.x & 7;
  const int bi = blockIdx.x >> 3;
  const int cap = bfill[b];
  const int stride = (gridDim.x >> 3) * blockDim.x;
  const unsigned* __restrict__ bp = pairs + ((size_t)b << bshift);
  for (int idx = bi * blockDim.x + threadIdx.x; idx < cap; idx += stride) {
    unsigned p = bp[idx];
    int c = (int)(p & 0xFFFFu);
    int pos = rptr2[c] + atomicAdd(&fillc[c], 1);
    srcs[pos] = (unsigned short)(p >> 16);
  }
}

// zero the 8 sentinel rows of each of the 3 slice tables
__global__ void k_zsent(float* __restrict__ Tall, int N) {
  int t = blockIdx.x * blockDim.x + threadIdx.x;
  if (t < CLS * 8 * 16) {
    int c = t / 128, rem = t % 128;
    int s = rem / 16, f = rem % 16;
    Tall[((size_t)c * 8 + s) * (size_t)(N + 1) * 16 + (size_t)N * 16 + f] = 0.f;
  }
}

// split conv_w into bf16 hi/lo, TRANSPOSED: WhT[cl][col][k]
__global__ void k_wsplit(const float* __restrict__ W, unsigned short* __restrict__ WhT,
                         unsigned short* __restrict__ WlT, int total) {
  int idx = blockIdx.x * blockDim.x + threadIdx.x;
  if (idx >= total) return;
  int cl = idx >> 14;
  int rem = idx & 16383;
  int c = rem >> 7, k = rem & 127;
  float w = W[(size_t)cl * 16384 + k * 128 + c];
  unsigned short h = bf16rne(w);
  WhT[idx] = h;
  WlT[idx] = bf16rne(w - bf16tof(h));
}

// ---- T0 = x * dinv, slice-major [8][N+1][16] ----
__global__ __launch_bounds__(256) void k_scale(const float* __restrict__ x,
                                               const float* __restrict__ dinv,
                                               float* __restrict__ T, int N) {
  const int s = blockIdx.y;
  const int i = blockIdx.x * 64 + (threadIdx.x >> 2);
  const int f = threadIdx.x & 3;
  if (i < N) {
    float4 v = *(const float4*)&x[(size_t)i * 128 + s * 16 + f * 4];
    float d = dinv[i];
    v.x *= d; v.y *= d; v.z *= d; v.w *= d;
    *(float4*)&T[((size_t)s * (N + 1) + i) * 16 + f * 4] = v;
  }
}

// ---- XCD-sliced gather, fused over classes (blockIdx.y = class); fp32 full-line out ----
__global__ __launch_bounds__(256, 4) void k_gather(const float* __restrict__ Tbase, long tstride,
                                                   const int* __restrict__ rptr2,
                                                   const unsigned short* __restrict__ srcs,
                                                   const float* __restrict__ dinv,
                                                   float* __restrict__ Zbase, long zstride,
                                                   int N) {
  const int s = blockIdx.x & 7;
  const int chunk = blockIdx.x >> 3;
  const int i = chunk * 64 + (threadIdx.x >> 2);
  const int f = threadIdx.x & 3;
  if (i >= N) return;
  const float* __restrict__ T = Tbase + (size_t)blockIdx.y * tstride;
  float* __restrict__ Z = Zbase + (size_t)blockIdx.y * zstride;
  const evf4* __restrict__ Ts = (const evf4*)(T + (size_t)s * (N + 1) * 16);
  const int e0 = rptr2[i], e1 = rptr2[i + 1];
  evf4 a0 = Ts[(size_t)i * 4 + f];  // self term
  evf4 a1 = (evf4)0.f, a2 = (evf4)0.f, a3 = (evf4)0.f;
  uint4 I0 = make_uint4(0, 0, 0, 0), I1 = I0;
  if (e0 < e1) {
    I0 = *(const uint4*)(srcs + e0);
    I1 = *(const uint4*)(srcs + e0 + 8);
  }
  for (int eb = e0; eb < e1; eb += 16) {
    uint4 I0n = I0, I1n = I1;
    if (eb + 16 < e1) {
      I0n = *(const uint4*)(srcs + eb + 16);
      I1n = *(const uint4*)(srcs + eb + 24);
    }
    const int j0  = (int)(I0.x & 0xFFFFu), j1  = (int)(I0.x >> 16);
    const int j2  = (int)(I0.y & 0xFFFFu), j3  = (int)(I0.y >> 16);
    const int j4  = (int)(I0.z & 0xFFFFu), j5  = (int)(I0.z >> 16);
    const int j6  = (int)(I0.w & 0xFFFFu), j7  = (int)(I0.w >> 16);
    const int j8  = (int)(I1.x & 0xFFFFu), j9  = (int)(I1.x >> 16);
    const int j10 = (int)(I1.y & 0xFFFFu), j11 = (int)(I1.y >> 16);
    const int j12 = (int)(I1.z & 0xFFFFu), j13 = (int)(I1.z >> 16);
    const int j14 = (int)(I1.w & 0xFFFFu), j15 = (int)(I1.w >> 16);
    evf4 v0  = Ts[(size_t)j0  * 4 + f];
    evf4 v1  = Ts[(size_t)j1  * 4 + f];
    evf4 v2  = Ts[(size_t)j2  * 4 + f];
    evf4 v3  = Ts[(size_t)j3  * 4 + f];
    evf4 v4  = Ts[(size_t)j4  * 4 + f];
    evf4 v5  = Ts[(size_t)j5  * 4 + f];
    evf4 v6  = Ts[(size_t)j6  * 4 + f];
    evf4 v7  = Ts[(size_t)j7  * 4 + f];
    evf4 v8  = Ts[(size_t)j8  * 4 + f];
    evf4 v9  = Ts[(size_t)j9  * 4 + f];
    evf4 v10 = Ts[(size_t)j10 * 4 + f];
    evf4 v11 = Ts[(size_t)j11 * 4 + f];
    evf4 v12 = Ts[(size_t)j12 * 4 + f];
    evf4 v13 = Ts[(size_t)j13 * 4 + f];
    evf4 v14 = Ts[(size_t)j14 * 4 + f];
    evf4 v15 = Ts[(size_t)j15 * 4 + f];
    asm volatile("" :: "v"(v0), "v"(v1), "v"(v2), "v"(v3),
                       "v"(v4), "v"(v5), "v"(v6), "v"(v7),
                       "v"(v8), "v"(v9), "v"(v10), "v"(v11),
                       "v"(v12), "v"(v13), "v"(v14), "v"(v15));
    __builtin_amdgcn_sched_barrier(0);
    a0 += v0;  a1 += v1;  a2 += v2;  a3 += v3;
    a0 += v4;  a1 += v5;  a2 += v6;  a3 += v7;
    a0 += v8;  a1 += v9;  a2 += v10; a3 += v11;
    a0 += v12; a1 += v13; a2 += v14; a3 += v15;
    I0 = I0n; I1 = I1n;
  }
  const float d = dinv[i];
  evf4 r = (a0 + a1 + a2 + a3) * d;
  *(evf4*)&Z[(size_t)i * 128 + s * 16 + f * 4] = r;
}

// ---- split-bf16 MFMA GEMM (emulated fp32), A split in-kernel from fp32 ----
// C = Ah@Wh + Ah@Wl + Al@Wh (Al@Wl dropped: ~2^-18 rel). 128x128 tile, 4 waves,
// K-step 32. MODE 0: slice-major fp32 table (+dinv); MODE 1: row-major fp32 H.
template <int MODE>
__global__ __launch_bounds__(256) void k_gemm3m(
    const float* __restrict__ Abase, long astride,
    const unsigned short* __restrict__ WhT, const unsigned short* __restrict__ WlT,
    int layer, const float* __restrict__ bl, const float* __restrict__ dinv,
    float* __restrict__ Obase, long ostride, int N) {
  __shared__ unsigned short Ash[128 * 40], Asl[128 * 40];
  __shared__ unsigned short Wsh[128 * 40], Wsl[128 * 40];
  __shared__ float red[128][2];

  const int c = blockIdx.y;
  const float* __restrict__ A = Abase + (size_t)c * astride;
  const size_t wslab = (size_t)(c * LAY + layer) * 16384;
  const float* __restrict__ bias = bl + (size_t)(c * LAY + layer) * D;
  float* __restrict__ Out = Obase + (size_t)c * ostride;

  const int tid = threadIdx.x;
  const int w = tid >> 6, l = tid & 63;
  const int wr = w >> 1, wc = w & 1;
  const int lg = l >> 4, li = l & 15;
  const int m0 = blockIdx.x * 128;

  f32x4 acc[4][4];
#pragma unroll
  for (int i = 0; i < 4; ++i)
#pragma unroll
    for (int j = 0; j < 4; ++j) acc[i][j] = (f32x4)0.f;

  const int srow = tid >> 1;
  const int half = tid & 1;
  const bool rowok = (m0 + srow) < N;

  for (int kc = 0; kc < 128; kc += 32) {
    float fa[16];
#pragma unroll
    for (int j = 0; j < 16; ++j) fa[j] = 0.f;
    if (rowok) {
      const size_t ab = (size_t)(m0 + srow) * 128 + kc + half * 16;
      *(float4*)&fa[0]  = *(const float4*)&A[ab];
      *(float4*)&fa[4]  = *(const float4*)&A[ab + 4];
      *(float4*)&fa[8]  = *(const float4*)&A[ab + 8];
      *(float4*)&fa[12] = *(const float4*)&A[ab + 12];
    }
    const size_t wb = wslab + (size_t)srow * 128 + kc + half * 16;
    uint4 wh0 = *(const uint4*)&WhT[wb];
    uint4 wh1 = *(const uint4*)&WhT[wb + 8];
    uint4 wl0 = *(const uint4*)&WlT[wb];
    uint4 wl1 = *(const uint4*)&WlT[wb + 8];

    unsigned hpk[8], lpk[8];
#pragma unroll
    for (int j = 0; j < 8; ++j) {
      unsigned short h0 = bf16rne(fa[2 * j]);
      unsigned short h1 = bf16rne(fa[2 * j + 1]);
      float l0 = fa[2 * j] - bf16tof(h0);
      float l1 = fa[2 * j + 1] - bf16tof(h1);
      hpk[j] = (unsigned)h0 | ((unsigned)h1 << 16);
      lpk[j] = (unsigned)bf16rne(l0) | ((unsigned)bf16rne(l1) << 16);
    }
    if (kc) __syncthreads();
    *(uint4*)&Ash[srow * 40 + half * 16]     = make_uint4(hpk[0], hpk[1], hpk[2], hpk[3]);
    *(uint4*)&Ash[srow * 40 + half * 16 + 8] = make_uint4(hpk[4], hpk[5], hpk[6], hpk[7]);
    *(uint4*)&Asl[srow * 40 + half * 16]     = make_uint4(lpk[0], lpk[1], lpk[2], lpk[3]);
    *(uint4*)&Asl[srow * 40 + half * 16 + 8] = make_uint4(lpk[4], lpk[5], lpk[6], lpk[7]);
    *(uint4*)&Wsh[srow * 40 + half * 16]     = wh0;
    *(uint4*)&Wsh[srow * 40 + half * 16 + 8] = wh1;
    *(uint4*)&Wsl[srow * 40 + half * 16]     = wl0;
    *(uint4*)&Wsl[srow * 40 + half * 16 + 8] = wl1;
    __syncthreads();

    bf16x8 fah[4], fal[4];
#pragma unroll
    for (int rf = 0; rf < 4; ++rf) {
      const int arow = wr * 64 + rf * 16 + li;
      fah[rf] = *(const bf16x8*)&Ash[arow * 40 + lg * 8];
      fal[rf] = *(const bf16x8*)&Asl[arow * 40 + lg * 8];
    }
#pragma unroll
    for (int cf = 0; cf < 4; ++cf) {
      const int bcol = wc * 64 + cf * 16 + li;
      bf16x8 fbh = *(const bf16x8*)&Wsh[bcol * 40 + lg * 8];
      bf16x8 fbl = *(const bf16x8*)&Wsl[bcol * 40 + lg * 8];
#pragma unroll
      for (int rf = 0; rf < 4; ++rf) {
        acc[rf][cf] = __builtin_amdgcn_mfma_f32_16x16x32_bf16(fah[rf], fbh, acc[rf][cf], 0, 0, 0);
        acc[rf][cf] = __builtin_amdgcn_mfma_f32_16x16x32_bf16(fah[rf], fbl, acc[rf][cf], 0, 0, 0);
        acc[rf][cf] = __builtin_amdgcn_mfma_f32_16x16x32_bf16(fal[rf], fbh, acc[rf][cf], 0, 0, 0);
      }
    }
  }
  __syncthreads();

  // epilogue: bias, row L2-norm (cross-lane + cross-wave), relu, (dinv), store
  float bj[4];
#pragma unroll
  for (int cf = 0; cf < 4; ++cf) bj[cf] = bias[wc * 64 + cf * 16 + li];
#pragma unroll
  for (int rf = 0; rf < 4; ++rf) {
#pragma unroll
    for (int r = 0; r < 4; ++r) {
      float sq = 0.f;
#pragma unroll
      for (int cf = 0; cf < 4; ++cf) {
        float v = acc[rf][cf][r] + bj[cf];
        acc[rf][cf][r] = v;
        sq = fmaf(v, v, sq);
      }
#pragma unroll
      for (int m = 1; m < 16; m <<= 1) sq += __shfl_xor(sq, m, 16);
      if (li == 0) red[wr * 64 + rf * 16 + lg * 4 + r][wc] = sq;
    }
  }
  __syncthreads();
#pragma unroll
  for (int rf = 0; rf < 4; ++rf) {
#pragma unroll
    for (int r = 0; r < 4; ++r) {
      const int rrow = wr * 64 + rf * 16 + lg * 4 + r;
      const int grow = m0 + rrow;
      if (grow >= N) continue;
      float rsum = red[rrow][0] + red[rrow][1];
      float sc = 1.0f / fmaxf(sqrtf(rsum), 1e-12f);
      if (MODE == 0) sc *= dinv[grow];
#pragma unroll
      for (int cf = 0; cf < 4; ++cf) {
        float v = fmaxf(acc[rf][cf][r] * sc, 0.f);
        if (MODE == 0) {
          const int sidx = wc * 4 + cf;
          Out[((size_t)sidx * (N + 1) + grow) * 16 + li] = v;
        } else {
          Out[(size_t)grow * 128 + wc * 64 + cf * 16 + li] = v;
        }
      }
    }
  }
}

// ------------- batched head: pool + lin1 + ReLU + lin2 (blockIdx.y = class) -------------
__device__ __forceinline__ int lowerb(const int* __restrict__ a, int n, int v) {
  int lo = 0, hi = n;
  while (lo < hi) {
    int m = (lo + hi) >> 1;
    if (a[m] < v) lo = m + 1; else hi = m;
  }
  return lo;
}

__global__ __launch_bounds__(128) void k_head(const float* __restrict__ Hall, long hstride,
                                              const int* __restrict__ batch, int N,
                                              const float* __restrict__ l1w,
                                              const float* __restrict__ l1b,
                                              const float* __restrict__ l2w,
                                              const float* __restrict__ l2b,
                                              float* __restrict__ out, int G) {
  const int g = blockIdx.x;
  const int c = blockIdx.y;
  const int t = threadIdx.x;
  const float* __restrict__ h = Hall + (size_t)c * hstride;
  const float* __restrict__ w1 = l1w + (size_t)c * D * D;
  const float* __restrict__ w2 = l2w + (size_t)c * D;
  int lo = lowerb(batch, N, g);
  int hi = lowerb(batch, N, g + 1);
  float p = 0.f;
  for (int i = lo; i < hi; ++i) p += h[(size_t)i * 128 + t];
  __shared__ float pl[128];
  pl[t] = p;
  __syncthreads();
  float z = l1b[(size_t)c * D + t];
#pragma unroll 8
  for (int k = 0; k < 128; ++k) z = fmaf(pl[k], w1[k * 128 + t], z);
  z = fmaxf(z, 0.f);
  float o = z * w2[t];
#pragma unroll
  for (int off = 32; off > 0; off >>= 1) o += __shfl_xor(o, off, 64);
  __shared__ float s2[2];
  if ((t & 63) == 0) s2[t >> 6] = o;
  __syncthreads();
  if (t == 0) out[(size_t)g * CLS + c] = s2[0] + s2[1] + l2b[c];
}

extern "C" void kernel_launch(void* const* d_in, const int* in_sizes, int n_in,
                              void* d_out, int out_size, void* d_ws, size_t ws_size,
                              hipStream_t stream) {
  const float* x = (const float*)d_in[0];
  const int* eidx = (const int*)d_in[1];
  const int* batch = (const int*)d_in[2];
  const float* conv_w = (const float*)d_in[3];
  const float* conv_b = (const float*)d_in[4];
  const float* lin1_w = (const float*)d_in[5];
  const float* lin1_b = (const float*)d_in[6];
  const float* lin2_w = (const float*)d_in[7];
  const float* lin2_b = (const float*)d_in[8];
  float* out = (float*)d_out;

  const int N = in_sizes[0] / D;
  const int E = in_sizes[1] / 2;
  const int G = out_size / CLS;
  const int* row = eidx;
  const int* col = eidx + E;

  int bshift = 10;
  while ((1 << bshift) < E / NBKT + 32768) ++bshift;
  const long TS = (long)(N + 1) * 128;  // per-class slice-table stride (floats)
  const long ZS = (long)N * 128;        // per-class row-major stride (floats)

  char* ws = (char*)d_ws;
  size_t off = 0;
  auto alloc = [&](size_t bytes) -> void* {
    void* p = ws + off;
    off += (bytes + 255) & ~(size_t)255;
    return p;
  };
  float* Zall = (float*)alloc((size_t)CLS * ZS * 4);
  float* Tall = (float*)alloc((size_t)CLS * TS * 4);
  unsigned short* WhT = (unsigned short*)alloc((size_t)CLS * LAY * D * D * 2);
  unsigned short* WlT = (unsigned short*)alloc((size_t)CLS * LAY * D * D * 2);
  unsigned short* srcs = (unsigned short*)alloc(((size_t)E + 16 * (size_t)N + 64) * 2);
  int* cnt    = (int*)alloc(((size_t)N * 2 + NBKT) * 4);
  int* fillc  = cnt + N;
  int* bfill  = cnt + 2 * N;
  int* rptr2  = (int*)alloc((size_t)(N + 1) * 4);
  float* dinv = (float*)alloc((size_t)N * 4);
  int* bsum   = (int*)alloc(1024 * 4 * 2);
  int* boff   = bsum + 1024;
  unsigned* pairs = (unsigned*)Tall;  // alias: dead before k_zsent/k_scale
  (void)ws_size; (void)n_in;

  hipMemsetAsync(cnt, 0, ((size_t)N * 2 + NBKT) * 4, stream);
  const int wtot = CLS * LAY * D * D;
  const int sb = (N + 255) / 256;
  k_bin<<<1024, 256, 0, stream>>>(row, col, cnt, bfill, pairs, E, (float)NBKT / (float)N, bshift);
  k_scanA<<<sb, 256, 0, stream>>>(cnt, bsum, N);
  k_scanB<<<1, 1024, 0, stream>>>(bsum, boff, rptr2 + N, sb);
  k_scanC<<<sb, 256, 0, stream>>>(cnt, boff, rptr2, dinv, srcs, N);
  k_fill2<<<1024, 256, 0, stream>>>(pairs, bfill, rptr2, fillc, srcs, bshift);
  k_zsent<<<2, 256, 0, stream>>>(Tall, N);
  k_wsplit<<<(wtot + 255) / 256, 256, 0, stream>>>(conv_w, WhT, WlT, wtot);

  const int NB64 = (N + 63) / 64;
  const int gb = (N + 127) / 128;
  float* Z0 = Zall;

  // shared layer 0
  k_scale<<<dim3(NB64, 8), 256, 0, stream>>>(x, dinv, Tall, N);
  k_gather<<<dim3(NB64 * 8, 1), 256, 0, stream>>>(Tall, 0L, rptr2, srcs, dinv, Z0, 0L, N);

  // layer 1 (A shared across classes)
  k_gemm3m<0><<<dim3(gb, CLS), 256, 0, stream>>>(Z0, 0L, WhT, WlT, 0,
                                                 conv_b, dinv, Tall, TS, N);
  k_gather<<<dim3(NB64 * 8, CLS), 256, 0, stream>>>(Tall, TS, rptr2, srcs, dinv, Zall, ZS, N);

  // layer 2
  k_gemm3m<0><<<dim3(gb, CLS), 256, 0, stream>>>(Zall, ZS, WhT, WlT, 1,
                                                 conv_b, dinv, Tall, TS, N);
  k_gather<<<dim3(NB64 * 8, CLS), 256, 0, stream>>>(Tall, TS, rptr2, srcs, dinv, Zall, ZS, N);

  // layer 3 -> H (row-major fp32, stored in the table slots)
  k_gemm3m<1><<<dim3(gb, CLS), 256, 0, stream>>>(Zall, ZS, WhT, WlT, 2,
                                                 conv_b, dinv, Tall, TS, N);

  // heads
  k_head<<<dim3(G, CLS), 128, 0, stream>>>(Tall, TS, batch, N,
                                           lin1_w, lin1_b, lin2_w, lin2_b, out, G);
}